// Round 5
// baseline (9.866 us; speedup 1.0000x reference)
//
#include <hip/hip_runtime.h>
#include <math.h>

// Multi-scale glimpse sensor — fused, LDS-staged single-launch version.
// img: (B, 224, 224, 3) f32, loc: (B, 2) f32 in [-1, 1]
// out: (B, 3, 16, 16, 3) f32
//
// Semantics (verified R1/R3/R4, absmax ~2e-4):
//  - cy = clip(floor((loc0+1)*0.5*H), 0, H), cx likewise
//  - scale i: patch side d = 16<<i, top-left (cy-d/2, cx-d/2) in image
//    coords; out-of-image pixels are ZERO (reference pads then slices).
//  - jax.image.resize bilinear antialias=True: s = d/16, T = 2s taps,
//    base weight 1-|t-(T-1)/2|/s, normalized PER AXIS over taps inside
//    the patch [0,d). d=16 => identity.
//
// R4 -> R5: patches are nested (32^2 and 16^2 are interior of the 64^2
// patch). Stage the 64x64x3 zero-padded patch in LDS once (4 coalesced
// 12B loads/lane @ 1024 threads, vs 21 scattered in R4), derive ALL
// scales from LDS. 1024 threads = 4 waves/SIMD for latency hiding.

#define IMG_H 224
#define IMG_W 224
#define ROWF  672               // 224*3 floats per image row
#define RSP   193               // patch/v2 row stride (64*3 + 1)
#define RS1   97                // v1 row stride (32*3 + 1)

struct F3 { float x, y, z; };
__device__ __forceinline__ F3 ld3(const float* p) { return *(const F3*)p; }

__global__ __launch_bounds__(1024, 1) void glimpse_kernel(
    const float* __restrict__ img, const float* __restrict__ loc,
    float* __restrict__ out) {
  __shared__ float patch[64 * RSP];   // 49.4 KB: zero-padded 64x64x3 patch
  __shared__ float v2[16 * RSP];      // 12.35 KB: vertical intermediate, s2
  __shared__ float v1[16 * RS1];      // 6.2 KB: vertical intermediate, s1

  const int b = blockIdx.x;
  const int tid = threadIdx.x;        // 0..1023

  const float ly = loc[b * 2 + 0];
  const float lx = loc[b * 2 + 1];
  int cy = (int)floorf((ly + 1.0f) * 0.5f * (float)IMG_H);
  int cx = (int)floorf((lx + 1.0f) * 0.5f * (float)IMG_W);
  cy = min(max(cy, 0), IMG_H);
  cx = min(max(cx, 0), IMG_W);
  const int oy0 = cy - 32;            // 64x64 patch top-left, image coords
  const int ox0 = cx - 32;

  const float* imgb = img + (size_t)b * IMG_H * ROWF;

  float wb2[8], wb1[4];
#pragma unroll
  for (int t = 0; t < 8; ++t) wb2[t] = 1.0f - fabsf((float)t - 3.5f) * 0.25f;
#pragma unroll
  for (int t = 0; t < 4; ++t) wb1[t] = 1.0f - fabsf((float)t - 1.5f) * 0.5f;

  // ---- stage: 64x64 patch -> LDS, zero outside image (coalesced) ----
#pragma unroll
  for (int it = 0; it < 4; ++it) {
    const int task = it * 1024 + tid;
    const int x = task & 63;          // lanes -> consecutive columns
    const int row = task >> 6;        // patch row, [0,64)
    const int yy = oy0 + row;
    const int xx = ox0 + x;
    const float we =
        (((unsigned)yy < IMG_H) && ((unsigned)xx < IMG_W)) ? 1.0f : 0.f;
    const int yc = min(max(yy, 0), IMG_H - 1);
    const int xc = min(max(xx, 0), IMG_W - 1);
    const F3 p = ld3(imgb + (size_t)yc * ROWF + (size_t)xc * 3);
    const int w = row * RSP + 3 * x;
    patch[w + 0] = we * p.x;
    patch[w + 1] = we * p.y;
    patch[w + 2] = we * p.z;
  }
  __syncthreads();

  // ---- vertical pass, scale 2 (all 1024 threads: i=[0,16), x=[0,64)) ----
  {
    const int x = tid & 63;
    const int i = tid >> 6;
    const int ky0 = 4 * i - 2;
    float a0 = 0.f, a1 = 0.f, a2 = 0.f;
#pragma unroll
    for (int t = 0; t < 8; ++t) {
      const int ky = ky0 + t;
      const float we = ((unsigned)ky < 64u) ? wb2[t] : 0.f;
      const int kc = min(max(ky, 0), 63);
      const int base = kc * RSP + 3 * x;
      a0 = fmaf(we, patch[base + 0], a0);
      a1 = fmaf(we, patch[base + 1], a1);
      a2 = fmaf(we, patch[base + 2], a2);
    }
    const float rsy = (i == 0 || i == 15) ? (1.0f / 3.5f) : 0.25f;
    const int w = i * RSP + 3 * x;
    v2[w + 0] = a0 * rsy;
    v2[w + 1] = a1 * rsy;
    v2[w + 2] = a2 * rsy;
  }

  // ---- vertical pass, scale 1 (threads 0-511: i=[0,16), x=[0,32)) ----
  if (tid < 512) {
    const int x = tid & 31;
    const int i = tid >> 5;
    const int ky0 = 2 * i - 1;
    float a0 = 0.f, a1 = 0.f, a2 = 0.f;
#pragma unroll
    for (int t = 0; t < 4; ++t) {
      const int ky = ky0 + t;
      const float we = ((unsigned)ky < 32u) ? wb1[t] : 0.f;
      const int kc = min(max(ky, 0), 31);
      const int base = (16 + kc) * RSP + 3 * (16 + x);   // interior region
      a0 = fmaf(we, patch[base + 0], a0);
      a1 = fmaf(we, patch[base + 1], a1);
      a2 = fmaf(we, patch[base + 2], a2);
    }
    const float rsy = (i == 0 || i == 15) ? (1.0f / 1.75f) : 0.5f;
    const int w = i * RS1 + 3 * x;
    v1[w + 0] = a0 * rsy;
    v1[w + 1] = a1 * rsy;
    v1[w + 2] = a2 * rsy;
  }

  // ---- scale 0: identity; copy interior [24,40)^2 of patch to out ----
  if (tid >= 512 && tid < 768) {
    const int px = tid - 512;
    const int jy = px >> 4;
    const int jx = px & 15;
    const int base = (24 + jy) * RSP + 3 * (24 + jx);
    float* o = out + ((size_t)(b * 3 + 0) * 256 + px) * 3;
    o[0] = patch[base + 0];
    o[1] = patch[base + 1];
    o[2] = patch[base + 2];
  }

  __syncthreads();

  // ---- horizontal pass + store ----
  if (tid < 256) {
    const int jy = tid >> 4;
    const int jx = tid & 15;
    const int kx0 = 4 * jx - 2;
    float a0 = 0.f, a1 = 0.f, a2 = 0.f;
#pragma unroll
    for (int t = 0; t < 8; ++t) {
      const int kx = kx0 + t;
      const float we = ((unsigned)kx < 64u) ? wb2[t] : 0.f;
      const int kc = min(max(kx, 0), 63);
      const int base = jy * RSP + 3 * kc;
      a0 = fmaf(we, v2[base + 0], a0);
      a1 = fmaf(we, v2[base + 1], a1);
      a2 = fmaf(we, v2[base + 2], a2);
    }
    const float rsx = (jx == 0 || jx == 15) ? (1.0f / 3.5f) : 0.25f;
    float* o = out + ((size_t)(b * 3 + 2) * 256 + tid) * 3;
    o[0] = a0 * rsx;
    o[1] = a1 * rsx;
    o[2] = a2 * rsx;
  } else if (tid < 512) {
    const int px = tid - 256;
    const int jy = px >> 4;
    const int jx = px & 15;
    const int kx0 = 2 * jx - 1;
    float a0 = 0.f, a1 = 0.f, a2 = 0.f;
#pragma unroll
    for (int t = 0; t < 4; ++t) {
      const int kx = kx0 + t;
      const float we = ((unsigned)kx < 32u) ? wb1[t] : 0.f;
      const int kc = min(max(kx, 0), 31);
      const int base = jy * RS1 + 3 * kc;
      a0 = fmaf(we, v1[base + 0], a0);
      a1 = fmaf(we, v1[base + 1], a1);
      a2 = fmaf(we, v1[base + 2], a2);
    }
    const float rsx = (jx == 0 || jx == 15) ? (1.0f / 1.75f) : 0.5f;
    float* o = out + ((size_t)(b * 3 + 1) * 256 + px) * 3;
    o[0] = a0 * rsx;
    o[1] = a1 * rsx;
    o[2] = a2 * rsx;
  }
}

extern "C" void kernel_launch(void* const* d_in, const int* in_sizes, int n_in,
                              void* d_out, int out_size, void* d_ws, size_t ws_size,
                              hipStream_t stream) {
  const float* img = (const float*)d_in[0];
  const float* loc = (const float*)d_in[1];
  float* out = (float*)d_out;
  const int B = in_sizes[1] / 2;      // loc is (B, 2)
  glimpse_kernel<<<B, 1024, 0, stream>>>(img, loc, out);
}